// Round 1
// baseline (37.412 us; speedup 1.0000x reference)
//
#include <hip/hip_runtime.h>

// y[b,u] = clip( sum_d x[b,d] ** exp2(w[d,u]) + bias[u], 0, 1 )
// Rewritten: inten = exp2( e[d,u] * lx[b,d] ), e = exp2(w), lx = log2(x).
// Trans-pipe bound: one v_exp_f32 per (b,d,u) element = 2.68e8 exp2's.

#define BT 32   // output rows (b) per block
#define UT 64   // output cols (u) per block
#define DK 64   // d-chunk staged in LDS

__global__ __launch_bounds__(256)
void fuzzy_intens_kernel(const float* __restrict__ x,   // [B][D]
                         const float* __restrict__ w,   // [D][U]
                         const float* __restrict__ bias,// [U]
                         float* __restrict__ out,       // [B][U]
                         int B, int D, int U)
{
    __shared__ float lxs[BT][DK + 1];  // log2(x) tile, +1 pad
    __shared__ float es[DK][UT];       // exp2(w) tile (b128-read friendly)

    const int tid = threadIdx.x;
    const int c = tid & 15;   // col group -> 4 consecutive u
    const int r = tid >> 4;   // row group -> 2 consecutive b
    const int u0 = blockIdx.x * UT;
    const int b0 = blockIdx.y * BT;

    const int lrow  = tid >> 4;        // 0..15 loader row
    const int lcol4 = (tid & 15) * 4;  // 0..60 loader col (float4)

    float acc[2][4];
    #pragma unroll
    for (int i = 0; i < 2; ++i)
        #pragma unroll
        for (int j = 0; j < 4; ++j) acc[i][j] = 0.f;

    for (int d0 = 0; d0 < D; d0 += DK) {
        // stage x tile -> log2 -> lxs  (BT x DK), 16 rows per pass
        #pragma unroll
        for (int p = 0; p < BT / 16; ++p) {
            const int row = p * 16 + lrow;
            const float4 v = *reinterpret_cast<const float4*>(
                &x[(size_t)(b0 + row) * D + d0 + lcol4]);
            lxs[row][lcol4 + 0] = __builtin_amdgcn_logf(v.x);
            lxs[row][lcol4 + 1] = __builtin_amdgcn_logf(v.y);
            lxs[row][lcol4 + 2] = __builtin_amdgcn_logf(v.z);
            lxs[row][lcol4 + 3] = __builtin_amdgcn_logf(v.w);
        }
        // stage w tile -> exp2 -> es (DK x UT), 16 rows per pass
        #pragma unroll
        for (int p = 0; p < DK / 16; ++p) {
            const int drow = p * 16 + lrow;
            const float4 v = *reinterpret_cast<const float4*>(
                &w[(size_t)(d0 + drow) * U + u0 + lcol4]);
            float4 e;
            e.x = __builtin_amdgcn_exp2f(v.x);
            e.y = __builtin_amdgcn_exp2f(v.y);
            e.z = __builtin_amdgcn_exp2f(v.z);
            e.w = __builtin_amdgcn_exp2f(v.w);
            *reinterpret_cast<float4*>(&es[drow][lcol4]) = e;
        }
        __syncthreads();

        #pragma unroll 4
        for (int d = 0; d < DK; ++d) {
            const float lx0 = lxs[2 * r + 0][d];
            const float lx1 = lxs[2 * r + 1][d];
            const float4 e = *reinterpret_cast<const float4*>(&es[d][4 * c]);
            acc[0][0] += __builtin_amdgcn_exp2f(e.x * lx0);
            acc[0][1] += __builtin_amdgcn_exp2f(e.y * lx0);
            acc[0][2] += __builtin_amdgcn_exp2f(e.z * lx0);
            acc[0][3] += __builtin_amdgcn_exp2f(e.w * lx0);
            acc[1][0] += __builtin_amdgcn_exp2f(e.x * lx1);
            acc[1][1] += __builtin_amdgcn_exp2f(e.y * lx1);
            acc[1][2] += __builtin_amdgcn_exp2f(e.z * lx1);
            acc[1][3] += __builtin_amdgcn_exp2f(e.w * lx1);
        }
        __syncthreads();
    }

    const float4 bv = *reinterpret_cast<const float4*>(&bias[u0 + 4 * c]);
    #pragma unroll
    for (int i = 0; i < 2; ++i) {
        float4 o;
        o.x = acc[i][0] + bv.x;
        o.y = acc[i][1] + bv.y;
        o.z = acc[i][2] + bv.z;
        o.w = acc[i][3] + bv.w;
        o.x = fminf(fmaxf(o.x, 0.f), 1.f);
        o.y = fminf(fmaxf(o.y, 0.f), 1.f);
        o.z = fminf(fmaxf(o.z, 0.f), 1.f);
        o.w = fminf(fmaxf(o.w, 0.f), 1.f);
        *reinterpret_cast<float4*>(
            &out[(size_t)(b0 + 2 * r + i) * U + u0 + 4 * c]) = o;
    }
}

extern "C" void kernel_launch(void* const* d_in, const int* in_sizes, int n_in,
                              void* d_out, int out_size, void* d_ws, size_t ws_size,
                              hipStream_t stream) {
    const float* x = (const float*)d_in[0];
    const float* w = (const float*)d_in[1];
    const float* b = (const float*)d_in[2];
    float* out = (float*)d_out;

    const int U = in_sizes[2];            // 512
    const int D = in_sizes[1] / U;        // 256
    const int B = in_sizes[0] / D;        // 2048

    dim3 grid(U / UT, B / BT);            // (8, 64) = 512 blocks
    dim3 block(256);
    fuzzy_intens_kernel<<<grid, block, 0, stream>>>(x, w, b, out, B, D, U);
}

// Round 2
// 33.486 us; speedup vs baseline: 1.1172x; 1.1172x over previous
//
#include <hip/hip_runtime.h>

// y[b,u] = clip( sum_d x[b,d] ** exp2(w[d,u]) + bias[u], 0, 1 )
// inten = exp2( e[d,u] * lx[b,d] ),  e = exp2(w), lx = log2(x).
// 2.68e8 v_exp_f32 total -> trans-pipe floor ~13.7us.
// R1: tile 32x32, 1024 blocks (4 waves/SIMD), 4 outputs/thread,
//     float2-packed mul/add (v_pk_*), 2 LDS instrs per d-step.

#define BT 32   // output rows (b) per block
#define UT 32   // output cols (u) per block
#define DK 64   // d-chunk staged in LDS

typedef float f2 __attribute__((ext_vector_type(2)));

__global__ __launch_bounds__(256)
void fuzzy_intens_kernel(const float* __restrict__ x,   // [B][D]
                         const float* __restrict__ w,   // [D][U]
                         const float* __restrict__ bias,// [U]
                         float* __restrict__ out,       // [B][U]
                         int B, int D, int U)
{
    __shared__ float lxs[BT][DK + 1];  // log2(x) tile
    __shared__ float es[DK][UT];       // exp2(w) tile

    const int tid = threadIdx.x;
    const int c = tid & 7;    // u-group: 4 consecutive u
    const int r = tid >> 3;   // row: 1 b each (0..31)
    const int u0 = blockIdx.x * UT;
    const int b0 = blockIdx.y * BT;

    f2 acc0 = {0.f, 0.f}, acc1 = {0.f, 0.f};

    const int lrow  = tid >> 4;        // x-loader: 16 rows/pass
    const int lcol4 = (tid & 15) * 4;
    const int erow  = tid >> 3;        // w-loader: 32 rows/pass
    const int ecol4 = (tid & 7) * 4;

    for (int d0 = 0; d0 < D; d0 += DK) {
        // stage log2(x): BT x DK
        #pragma unroll
        for (int p = 0; p < BT / 16; ++p) {
            const int row = p * 16 + lrow;
            const float4 v = *reinterpret_cast<const float4*>(
                &x[(size_t)(b0 + row) * D + d0 + lcol4]);
            lxs[row][lcol4 + 0] = __builtin_amdgcn_logf(v.x);
            lxs[row][lcol4 + 1] = __builtin_amdgcn_logf(v.y);
            lxs[row][lcol4 + 2] = __builtin_amdgcn_logf(v.z);
            lxs[row][lcol4 + 3] = __builtin_amdgcn_logf(v.w);
        }
        // stage exp2(w): DK x UT
        #pragma unroll
        for (int p = 0; p < DK / 32; ++p) {
            const int drow = p * 32 + erow;
            const float4 v = *reinterpret_cast<const float4*>(
                &w[(size_t)(d0 + drow) * U + u0 + ecol4]);
            float4 e;
            e.x = __builtin_amdgcn_exp2f(v.x);
            e.y = __builtin_amdgcn_exp2f(v.y);
            e.z = __builtin_amdgcn_exp2f(v.z);
            e.w = __builtin_amdgcn_exp2f(v.w);
            *reinterpret_cast<float4*>(&es[drow][ecol4]) = e;
        }
        __syncthreads();

        #pragma unroll 8
        for (int d = 0; d < DK; ++d) {
            const float lx = lxs[r][d];
            const f2* ep = reinterpret_cast<const f2*>(&es[d][4 * c]);
            const f2 e0 = ep[0];
            const f2 e1 = ep[1];
            const f2 lx2 = {lx, lx};
            const f2 p0 = e0 * lx2;     // v_pk_mul_f32
            const f2 p1 = e1 * lx2;
            f2 t0, t1;
            t0.x = __builtin_amdgcn_exp2f(p0.x);
            t0.y = __builtin_amdgcn_exp2f(p0.y);
            t1.x = __builtin_amdgcn_exp2f(p1.x);
            t1.y = __builtin_amdgcn_exp2f(p1.y);
            acc0 += t0;                 // v_pk_add_f32
            acc1 += t1;
        }
        __syncthreads();
    }

    const float4 bv = *reinterpret_cast<const float4*>(&bias[u0 + 4 * c]);
    float4 o;
    o.x = fminf(fmaxf(acc0.x + bv.x, 0.f), 1.f);
    o.y = fminf(fmaxf(acc0.y + bv.y, 0.f), 1.f);
    o.z = fminf(fmaxf(acc1.x + bv.z, 0.f), 1.f);
    o.w = fminf(fmaxf(acc1.y + bv.w, 0.f), 1.f);
    *reinterpret_cast<float4*>(&out[(size_t)(b0 + r) * U + u0 + 4 * c]) = o;
}

extern "C" void kernel_launch(void* const* d_in, const int* in_sizes, int n_in,
                              void* d_out, int out_size, void* d_ws, size_t ws_size,
                              hipStream_t stream) {
    const float* x = (const float*)d_in[0];
    const float* w = (const float*)d_in[1];
    const float* b = (const float*)d_in[2];
    float* out = (float*)d_out;

    const int U = in_sizes[2];            // 512
    const int D = in_sizes[1] / U;        // 256
    const int B = in_sizes[0] / D;        // 2048

    dim3 grid(U / UT, B / BT);            // (16, 64) = 1024 blocks
    dim3 block(256);
    fuzzy_intens_kernel<<<grid, block, 0, stream>>>(x, w, b, out, B, D, U);
}